// Round 11
// baseline (259.344 us; speedup 1.0000x reference)
//
#include <hip/hip_runtime.h>
#include <hip/hip_bf16.h>
#include <cstddef>

// Problem constants (match reference)
constexpr int NN = 20000;   // nodes
constexpr int NE = 320000;  // edges
constexpr int NHEAD = 4;
constexpr int ND = 128;     // per-head dim
constexpr int HD = 512;     // H*D
constexpr int MPAD = 20096; // 157*128 padded rows for GEMM tiles
constexpr int SLOTS = 64;   // padded-CSR slots per node (Poisson(16): P(>64)~1e-20)
constexpr float NEG_SLOPE = 0.2f;

using short8 = __attribute__((ext_vector_type(8))) short;
using f32x4 = __attribute__((ext_vector_type(4))) float;
using f32x2 = __attribute__((ext_vector_type(2))) float;

// async global->LDS, 16B per lane, LDS dest = wave-uniform base + lane*16
__device__ inline void gload16(const void* g, void* l) {
  __builtin_amdgcn_global_load_lds(
      (const __attribute__((address_space(1))) void*)g,
      (__attribute__((address_space(3))) void*)l, 16, 0, 0);
}

// fp8 e4m3 (OCP on gfx950) encode one float -> byte
__device__ inline unsigned char f32_to_fp8(float v) {
  int pk = __builtin_amdgcn_cvt_pk_fp8_f32(v, v, 0, false);
  return (unsigned char)(pk & 0xff);
}

// ---------------- fused prep + padded-CSR fill ------------------------------
// Segments: [fill edges][feats->bf16 pad][W1^T bf16][vcomb = W2-folded layer-2
// projection vectors][partials zero][done zero]
// vcomb[v][k], v = 0..11: v<4 -> vl[h=v], v<8 -> vr[h=v-4], else vq[h=v-8]:
//   vl[h,k] = sum_d W2[k, h*128+d] * al2[h,d]   (el2 = h1 . vl, fp32 — the
//   attention logits keep full precision; this is what killed R10's fp8 GEMM2)
constexpr int S0 = NE;
constexpr int S1 = S0 + MPAD * 128;
constexpr int S2 = S1 + 512 * 128;
constexpr int S3 = S2 + 12 * 512;
constexpr int S4 = S3 + 256;
constexpr int S5 = S4 + 16;
__global__ __launch_bounds__(256) void prep_kernel(
    const float* __restrict__ feats, const float* __restrict__ W1,
    const float* __restrict__ W2, const float* __restrict__ al2,
    const float* __restrict__ ar2, const float* __restrict__ Wr,
    const int* __restrict__ src, const int* __restrict__ dst,
    __hip_bfloat16* __restrict__ featsb, __hip_bfloat16* __restrict__ W1t,
    float* __restrict__ vcomb, float* __restrict__ partials,
    unsigned int* __restrict__ done,
    int* __restrict__ cnt, int* __restrict__ src_perm) {
  int t = blockIdx.x * 256 + threadIdx.x;
  if (t < S0) {
    int d = dst[t];
    int p = atomicAdd(&cnt[d], 1);
    if (p < SLOTS) src_perm[d * SLOTS + p] = src[t];
  } else if (t < S1) {
    int u = t - S0;
    featsb[u] = __float2bfloat16(u < NN * 128 ? feats[u] : 0.f);
  } else if (t < S2) {
    int u = t - S1;                       // W1t[m][k], m=u>>7, k=u&127
    W1t[u] = __float2bfloat16(W1[(size_t)(u & 127) * 512 + (u >> 7)]);
  } else if (t < S3) {
    int u = t - S2;                       // vcomb[v][k]
    int v = u >> 9, k = u & 511;
    int h = (v < 4) ? v : (v < 8) ? v - 4 : v - 8;
    const float* vec = (v < 4) ? (al2 + h * 128)
                     : (v < 8) ? (ar2 + h * 128) : Wr;
    const float* wrow = W2 + (size_t)k * 512 + h * 128;
    float s = 0.f;
    for (int d = 0; d < 128; ++d) s += wrow[d] * vec[d];
    vcomb[u] = s;
  } else if (t < S4) {
    partials[t - S3] = 0.f;
  } else if (t < S5) {
    if (t == S4) *done = 0u;
  }
}

// ---------------- layer-1 bf16 MFMA GEMM + fused el/er epilogue, fp8 z ------
// z[Mpad][512] (fp8 e4m3) = A[Mpad][128] @ W1t[512][128]^T.  128x128 tile,
// 256 threads = 4 waves, each 64x64 via 4x4 mfma_16x16x32.  blockIdx.y = head
// (D=128 = tile width); el/er reduced from the fp32 accumulators (full
// precision — logits must not be quantized).  z fp8: payload only.
__global__ __launch_bounds__(256) void gemm1_kernel(
    const __hip_bfloat16* __restrict__ A,   // [Mpad][128] bf16
    const __hip_bfloat16* __restrict__ Bt,  // [512][128] bf16 (W1^T)
    unsigned char* __restrict__ C,          // [Mpad][512] fp8
    const float* __restrict__ al, const float* __restrict__ ar,
    float* __restrict__ el, float* __restrict__ er) {
  constexpr int K = 128;
  __shared__ short As[128 * 32];
  __shared__ short Bs[128 * 32];
  __shared__ float elbuf[4][128];
  __shared__ float erbuf[4][128];
  int t = threadIdx.x;
  int lane = t & 63;
  int wave = t >> 6;
  int rowBase = blockIdx.x * 128;
  int head = blockIdx.y;
  int colBase = head * 128;
  int woffr = (wave & 1) * 64;
  int woffc = (wave >> 1) * 64;
  int mrow = lane & 15, quad = lane >> 4;

  f32x4 acc[4][4];
#pragma unroll
  for (int i = 0; i < 4; ++i)
#pragma unroll
    for (int j = 0; j < 4; ++j) acc[i][j] = (f32x4){0.f, 0.f, 0.f, 0.f};

  for (int k0 = 0; k0 < K; k0 += 32) {
#pragma unroll
    for (int p = 0; p < 2; ++p) {
      int f = p * 256 + wave * 64 + lane;
      int r = f >> 2, kc = f & 3;
      gload16(A + (size_t)(rowBase + r) * K + k0 + kc * 8,
              As + p * 2048 + wave * 512);
      gload16(Bt + (size_t)(colBase + r) * K + k0 + kc * 8,
              Bs + p * 2048 + wave * 512);
    }
    __syncthreads();
    short8 af[4], bfr[4];
#pragma unroll
    for (int i = 0; i < 4; ++i)
      af[i] = *(const short8*)&As[(woffr + i * 16 + mrow) * 32 + quad * 8];
#pragma unroll
    for (int j = 0; j < 4; ++j)
      bfr[j] = *(const short8*)&Bs[(woffc + j * 16 + mrow) * 32 + quad * 8];
#pragma unroll
    for (int i = 0; i < 4; ++i)
#pragma unroll
      for (int j = 0; j < 4; ++j)
        acc[i][j] = __builtin_amdgcn_mfma_f32_16x16x32_bf16(af[i], bfr[j], acc[i][j], 0, 0, 0);
    __syncthreads();
  }

  // z store (fp8). C/D layout: col = lane&15, row = quad*4 + reg (m89/m91)
#pragma unroll
  for (int i = 0; i < 4; ++i) {
#pragma unroll
    for (int j = 0; j < 4; ++j) {
      int col = colBase + woffc + j * 16 + mrow;
#pragma unroll
      for (int r = 0; r < 4; ++r) {
        int row = rowBase + woffr + i * 16 + quad * 4 + r;
        C[(size_t)row * HD + col] = f32_to_fp8(acc[i][j][r]);
      }
    }
  }

  // fused el/er epilogue from fp32 accumulators
  float al_v[4], ar_v[4];
#pragma unroll
  for (int j = 0; j < 4; ++j) {
    int coll = woffc + j * 16 + mrow;
    al_v[j] = al[head * 128 + coll];
    ar_v[j] = ar[head * 128 + coll];
  }
#pragma unroll
  for (int i = 0; i < 4; ++i) {
#pragma unroll
    for (int r = 0; r < 4; ++r) {
      float pl = 0.f, pr = 0.f;
#pragma unroll
      for (int j = 0; j < 4; ++j) {
        float v = acc[i][j][r];
        pl += v * al_v[j];
        pr += v * ar_v[j];
      }
#pragma unroll
      for (int off = 1; off < 16; off <<= 1) {
        pl += __shfl_xor(pl, off);
        pr += __shfl_xor(pr, off);
      }
      if (mrow == 0) {
        int row128 = woffr + i * 16 + quad * 4 + r;
        elbuf[wave][row128] = pl;
        erbuf[wave][row128] = pr;
      }
    }
  }
  __syncthreads();
  if (t < 128) {
    int row = t;
    int w0 = (row < 64) ? 0 : 1;
    float ev = elbuf[w0][row] + elbuf[w0 + 2][row];
    float rv = erbuf[w0][row] + erbuf[w0 + 2][row];
    int gr = rowBase + row;
    if (gr < NN) {
      el[gr * 4 + head] = ev;
      er[gr * 4 + head] = rv;
    }
  }
}

// ---------------- fused attn + aggregation + layer-2 projection -------------
// One wave per node (proven R9 structure).
// Phase 1 (lane = slot): alpha via exp(leaky_relu(el1[src]+er1[n])) (softmax
// shift-invariance -> segment_max skipped), butterfly denom, alpha -> LDS.
// Phase 2 (lane = dims): h1[n, lane*8..+8) = ELU(sum_e alpha*z[src] + b1) in
// fp32 registers.
// Epilogue: h1 is NEVER stored — el2/er2/q are produced directly as 12 dot
// products with the W2-folded vcomb vectors (GEMM2 eliminated algebraically;
// logits stay fp32).
__global__ __launch_bounds__(256) void aggregate_kernel(
    const unsigned char* __restrict__ zf8,  // [MPAD][512] fp8
    const int* __restrict__ cnt,
    const int* __restrict__ src_perm,
    const float* __restrict__ el,           // layer-1 logits [NN][4]
    const float* __restrict__ er,
    const float* __restrict__ b1,           // [512]
    const float* __restrict__ vcomb,        // [12][512]
    float* __restrict__ el2,                // [NN][4]
    float* __restrict__ er2,                // [NN][4]
    float* __restrict__ q2) {               // [NN][4]
  __shared__ float4 alds[4][SLOTS];
  int wv = __builtin_amdgcn_readfirstlane((int)(threadIdx.x >> 6));
  int n = blockIdx.x * 4 + wv;
  int lane = threadIdx.x & 63;
  int c = min(cnt[n], SLOTS);
  int base = n * SLOTS;

  // ---- phase 1: attention coefficients (lane = slot) ----
  {
    float4 er4 = *reinterpret_cast<const float4*>(&er[n * 4]);
    float a0 = 0.f, a1 = 0.f, a2 = 0.f, a3 = 0.f;
    if (lane < c) {
      int s = src_perm[base + lane];
      float4 e4 = *reinterpret_cast<const float4*>(&el[s * 4]);
      float x0 = e4.x + er4.x, x1 = e4.y + er4.y;
      float x2 = e4.z + er4.z, x3 = e4.w + er4.w;
      x0 = (x0 > 0.f) ? x0 : NEG_SLOPE * x0;
      x1 = (x1 > 0.f) ? x1 : NEG_SLOPE * x1;
      x2 = (x2 > 0.f) ? x2 : NEG_SLOPE * x2;
      x3 = (x3 > 0.f) ? x3 : NEG_SLOPE * x3;
      a0 = __expf(x0); a1 = __expf(x1); a2 = __expf(x2); a3 = __expf(x3);
    }
    float s0 = a0, s1 = a1, s2 = a2, s3 = a3;
#pragma unroll
    for (int off = 1; off < 64; off <<= 1) {
      s0 += __shfl_xor(s0, off);
      s1 += __shfl_xor(s1, off);
      s2 += __shfl_xor(s2, off);
      s3 += __shfl_xor(s3, off);
    }
    float4 av;
    av.x = a0 / fmaxf(s0, 1e-9f);
    av.y = a1 / fmaxf(s1, 1e-9f);
    av.z = a2 / fmaxf(s2, 1e-9f);
    av.w = a3 / fmaxf(s3, 1e-9f);
    alds[wv][lane] = av;   // same-wave producer/consumer
  }

  // ---- phase 2: payload aggregation (lane = dims) ----
  int head = lane >> 4;
  float acc[8] = {};

#define EDGE_BODY(IDX)                                                         \
  {                                                                            \
    int s = src_perm[base + (IDX)];                                            \
    float4 a4 = alds[wv][(IDX)];                                               \
    float a = (head & 2) ? ((head & 1) ? a4.w : a4.z)                          \
                         : ((head & 1) ? a4.y : a4.x);                         \
    uint2 w = *reinterpret_cast<const uint2*>(zf8 + (size_t)s * 512 + lane * 8); \
    f32x2 f0 = __builtin_amdgcn_cvt_pk_f32_fp8(w.x, false);                    \
    f32x2 f1 = __builtin_amdgcn_cvt_pk_f32_fp8(w.x, true);                     \
    f32x2 f2 = __builtin_amdgcn_cvt_pk_f32_fp8(w.y, false);                    \
    f32x2 f3 = __builtin_amdgcn_cvt_pk_f32_fp8(w.y, true);                     \
    acc[0] += a * f0.x; acc[1] += a * f0.y;                                    \
    acc[2] += a * f1.x; acc[3] += a * f1.y;                                    \
    acc[4] += a * f2.x; acc[5] += a * f2.y;                                    \
    acc[6] += a * f3.x; acc[7] += a * f3.y;                                    \
  }

  int i = 0;
  for (; i + 3 < c; i += 4) {
    EDGE_BODY(i)
    EDGE_BODY(i + 1)
    EDGE_BODY(i + 2)
    EDGE_BODY(i + 3)
  }
  for (; i < c; ++i) EDGE_BODY(i)
#undef EDGE_BODY

  float4 bA = *reinterpret_cast<const float4*>(&b1[lane * 8]);
  float4 bB = *reinterpret_cast<const float4*>(&b1[lane * 8 + 4]);
  float v[8];
  v[0] = acc[0] + bA.x; v[1] = acc[1] + bA.y;
  v[2] = acc[2] + bA.z; v[3] = acc[3] + bA.w;
  v[4] = acc[4] + bB.x; v[5] = acc[5] + bB.y;
  v[6] = acc[6] + bB.z; v[7] = acc[7] + bB.w;
#pragma unroll
  for (int j = 0; j < 8; ++j) v[j] = (v[j] > 0.f) ? v[j] : expm1f(v[j]);

  // ---- epilogue: el2/er2/q = h1 . vcomb (12 dots, butterfly reductions) ----
  float r[12];
#pragma unroll
  for (int vv = 0; vv < 12; ++vv) {
    const float* vb = vcomb + vv * 512 + lane * 8;
    float4 cA = *reinterpret_cast<const float4*>(vb);
    float4 cB = *reinterpret_cast<const float4*>(vb + 4);
    float p = v[0] * cA.x + v[1] * cA.y + v[2] * cA.z + v[3] * cA.w +
              v[4] * cB.x + v[5] * cB.y + v[6] * cB.z + v[7] * cB.w;
#pragma unroll
    for (int off = 1; off < 64; off <<= 1) p += __shfl_xor(p, off);
    r[vv] = p;
  }
  if (lane == 0) {
    *reinterpret_cast<float4*>(&el2[n * 4]) = make_float4(r[0], r[1], r[2], r[3]);
    *reinterpret_cast<float4*>(&er2[n * 4]) = make_float4(r[4], r[5], r[6], r[7]);
    *reinterpret_cast<float4*>(&q2[n * 4]) = make_float4(r[8], r[9], r[10], r[11]);
  }
}

// ---------------- layer-2 attention + readout dot + grid-final --------------
// One wave per dst node (lane = slot): alpha butterfly, dot with q[src] (16 B
// L2-resident gather), block partial -> 256-slot atomics.  Last-done block
// (device-scope done counter) reduces partials + analytic bias term:
// out = 0.25*(sum_e alpha.q[src] + NN*b2.Wr_rep) + NN*br
__global__ __launch_bounds__(256) void attn_q_kernel(
    const int* __restrict__ src_perm,
    const int* __restrict__ cnt,
    const float* __restrict__ el,
    const float* __restrict__ er,
    const float* __restrict__ q,            // [NN][4]
    float* __restrict__ partials,           // [256]
    unsigned int* __restrict__ done,
    const float* __restrict__ b2, const float* __restrict__ Wr,
    const float* __restrict__ br, float* __restrict__ out) {
  __shared__ float blk[4];
  __shared__ float tmp[256];
  __shared__ int lastflag;
  int wv = __builtin_amdgcn_readfirstlane((int)(threadIdx.x >> 6));
  int n = blockIdx.x * 4 + wv;
  int lane = threadIdx.x & 63;
  int c = min(cnt[n], SLOTS);
  float4 er4 = *reinterpret_cast<const float4*>(&er[n * 4]);
  float a0 = 0.f, a1 = 0.f, a2 = 0.f, a3 = 0.f;
  int s = 0;
  if (lane < c) {
    s = src_perm[n * SLOTS + lane];
    float4 e4 = *reinterpret_cast<const float4*>(&el[s * 4]);
    float x0 = e4.x + er4.x, x1 = e4.y + er4.y;
    float x2 = e4.z + er4.z, x3 = e4.w + er4.w;
    x0 = (x0 > 0.f) ? x0 : NEG_SLOPE * x0;
    x1 = (x1 > 0.f) ? x1 : NEG_SLOPE * x1;
    x2 = (x2 > 0.f) ? x2 : NEG_SLOPE * x2;
    x3 = (x3 > 0.f) ? x3 : NEG_SLOPE * x3;
    a0 = __expf(x0); a1 = __expf(x1); a2 = __expf(x2); a3 = __expf(x3);
  }
  float s0 = a0, s1 = a1, s2 = a2, s3 = a3;
#pragma unroll
  for (int off = 1; off < 64; off <<= 1) {
    s0 += __shfl_xor(s0, off);
    s1 += __shfl_xor(s1, off);
    s2 += __shfl_xor(s2, off);
    s3 += __shfl_xor(s3, off);
  }
  float p = 0.f;
  if (lane < c) {
    float4 q4 = *reinterpret_cast<const float4*>(&q[s * 4]);
    p = (a0 / fmaxf(s0, 1e-9f)) * q4.x + (a1 / fmaxf(s1, 1e-9f)) * q4.y +
        (a2 / fmaxf(s2, 1e-9f)) * q4.z + (a3 / fmaxf(s3, 1e-9f)) * q4.w;
  }
#pragma unroll
  for (int off = 32; off > 0; off >>= 1) p += __shfl_down(p, off);
  if (lane == 0) blk[wv] = p;
  __syncthreads();
  if (threadIdx.x == 0) {
    atomicAdd(&partials[blockIdx.x & 255], blk[0] + blk[1] + blk[2] + blk[3]);
    __threadfence();
    unsigned prev = atomicAdd(done, 1u);
    lastflag = (prev == gridDim.x - 1) ? 1 : 0;
  }
  __syncthreads();
  if (lastflag) {
    int t = threadIdx.x;
    float sum = atomicAdd(&partials[t], 0.0f);   // coherent read
    sum += (float)NN * (b2[t] + b2[t + 256]) * Wr[t & 127];
    tmp[t] = sum;
    __syncthreads();
    for (int off = 128; off > 0; off >>= 1) {
      if (t < off) tmp[t] += tmp[t + off];
      __syncthreads();
    }
    if (t == 0) out[0] = 0.25f * tmp[0] + (float)NN * br[0];
  }
}

// ---------------- launch ----------------
extern "C" void kernel_launch(void* const* d_in, const int* in_sizes, int n_in,
                              void* d_out, int out_size, void* d_ws, size_t ws_size,
                              hipStream_t stream) {
  const float* feats = (const float*)d_in[0];
  const int* src = (const int*)d_in[1];
  const int* dst = (const int*)d_in[2];
  const float* W1 = (const float*)d_in[3];
  const float* al1 = (const float*)d_in[4];
  const float* ar1 = (const float*)d_in[5];
  const float* b1 = (const float*)d_in[6];
  const float* W2 = (const float*)d_in[7];
  const float* al2 = (const float*)d_in[8];
  const float* ar2 = (const float*)d_in[9];
  const float* b2 = (const float*)d_in[10];
  const float* Wr = (const float*)d_in[11];
  const float* br = (const float*)d_in[12];
  float* out = (float*)d_out;

  // workspace layout (~22 MB); all section sizes multiples of 16 B
  __hip_bfloat16* featsb = (__hip_bfloat16*)d_ws;               // MPAD*128 bf16
  unsigned char* zf8 = (unsigned char*)(featsb + (size_t)MPAD * 128); // MPAD*512 fp8
  __hip_bfloat16* W1t = (__hip_bfloat16*)(zf8 + (size_t)MPAD * HD);   // 512*128 bf16
  float* vcomb = (float*)(W1t + 512 * 128);                     // 12*512 f32
  float* el1 = vcomb + 12 * 512;                                // NN*4
  float* er1 = el1 + (size_t)NN * NHEAD;                        // NN*4
  float* el2 = er1 + (size_t)NN * NHEAD;                        // NN*4
  float* er2 = el2 + (size_t)NN * NHEAD;                        // NN*4
  float* q2 = er2 + (size_t)NN * NHEAD;                         // NN*4
  float* partials = q2 + (size_t)NN * NHEAD;                    // 256
  unsigned int* done = (unsigned int*)(partials + 256);         // 4 (pad 16B)
  int* cnt = (int*)(done + 4);                                  // NN
  int* src_perm = cnt + NN;                                     // NN*SLOTS

  // cnt must be zero before prep's fill segment runs
  hipMemsetAsync(cnt, 0, NN * sizeof(int), stream);
  prep_kernel<<<(S5 + 255) / 256, 256, 0, stream>>>(
      feats, W1, W2, al2, ar2, Wr, src, dst, featsb, W1t, vcomb, partials,
      done, cnt, src_perm);

  dim3 gemm_grid(MPAD / 128, NHEAD);

  // ---- layer 1: GEMM (fp8 z + el/er) ----
  gemm1_kernel<<<gemm_grid, 256, 0, stream>>>(featsb, W1t, zf8, al1, ar1, el1, er1);

  // ---- fused: layer-1 attn+aggregate + layer-2 projections (GEMM2 folded) ---
  aggregate_kernel<<<NN / 4, 256, 0, stream>>>(zf8, cnt, src_perm, el1, er1, b1,
                                               vcomb, el2, er2, q2);

  // ---- layer-2 attention + readout + final (grid-fused) ----
  attn_q_kernel<<<NN / 4, 256, 0, stream>>>(src_perm, cnt, el2, er2, q2,
                                            partials, done, b2, Wr, br, out);
}

// Round 12
// 178.848 us; speedup vs baseline: 1.4501x; 1.4501x over previous
//
#include <hip/hip_runtime.h>
#include <hip/hip_bf16.h>
#include <cstddef>

// Problem constants (match reference)
constexpr int NN = 20000;   // nodes
constexpr int NE = 320000;  // edges
constexpr int NHEAD = 4;
constexpr int ND = 128;     // per-head dim
constexpr int HD = 512;     // H*D
constexpr int MPAD = 20096; // 157*128 padded rows for GEMM tiles
constexpr int SLOTS = 64;   // padded-CSR slots per node (Poisson(16): P(>64)~1e-20)
constexpr float NEG_SLOPE = 0.2f;

using short8 = __attribute__((ext_vector_type(8))) short;
using f32x4 = __attribute__((ext_vector_type(4))) float;
using f32x2 = __attribute__((ext_vector_type(2))) float;

// async global->LDS, 16B per lane, LDS dest = wave-uniform base + lane*16
__device__ inline void gload16(const void* g, void* l) {
  __builtin_amdgcn_global_load_lds(
      (const __attribute__((address_space(1))) void*)g,
      (__attribute__((address_space(3))) void*)l, 16, 0, 0);
}

// fp8 e4m3 (OCP on gfx950) encode one float -> byte
__device__ inline unsigned char f32_to_fp8(float v) {
  int pk = __builtin_amdgcn_cvt_pk_fp8_f32(v, v, 0, false);
  return (unsigned char)(pk & 0xff);
}

// ---------------- fused prep + padded-CSR fill ------------------------------
// Segments: [fill edges][feats->bf16 pad][W1^T bf16][vcomb = W2-folded layer-2
// projection vectors][partials zero]
// vcomb[v][k], v = 0..11: v<4 -> vl[h=v], v<8 -> vr[h=v-4], else vq[h=v-8]:
//   vl[h,k] = sum_d W2[k, h*128+d] * al2[h,d]   (el2 = h1 . vl, fp32 — the
//   attention logits keep full precision; fp8 logits failed in R10)
constexpr int S0 = NE;
constexpr int S1 = S0 + MPAD * 128;
constexpr int S2 = S1 + 512 * 128;
constexpr int S3 = S2 + 12 * 512;
constexpr int S4 = S3 + 256;
__global__ __launch_bounds__(256) void prep_kernel(
    const float* __restrict__ feats, const float* __restrict__ W1,
    const float* __restrict__ W2, const float* __restrict__ al2,
    const float* __restrict__ ar2, const float* __restrict__ Wr,
    const int* __restrict__ src, const int* __restrict__ dst,
    __hip_bfloat16* __restrict__ featsb, __hip_bfloat16* __restrict__ W1t,
    float* __restrict__ vcomb, float* __restrict__ partials,
    int* __restrict__ cnt, int* __restrict__ src_perm) {
  int t = blockIdx.x * 256 + threadIdx.x;
  if (t < S0) {
    int d = dst[t];
    int p = atomicAdd(&cnt[d], 1);
    if (p < SLOTS) src_perm[d * SLOTS + p] = src[t];
  } else if (t < S1) {
    int u = t - S0;
    featsb[u] = __float2bfloat16(u < NN * 128 ? feats[u] : 0.f);
  } else if (t < S2) {
    int u = t - S1;                       // W1t[m][k], m=u>>7, k=u&127
    W1t[u] = __float2bfloat16(W1[(size_t)(u & 127) * 512 + (u >> 7)]);
  } else if (t < S3) {
    int u = t - S2;                       // vcomb[v][k]
    int v = u >> 9, k = u & 511;
    int h = (v < 4) ? v : (v < 8) ? v - 4 : v - 8;
    const float* vec = (v < 4) ? (al2 + h * 128)
                     : (v < 8) ? (ar2 + h * 128) : Wr;
    const float* wrow = W2 + (size_t)k * 512 + h * 128;
    float s = 0.f;
    for (int d = 0; d < 128; ++d) s += wrow[d] * vec[d];
    vcomb[u] = s;
  } else if (t < S4) {
    partials[t - S3] = 0.f;
  }
}

// ---------------- layer-1 bf16 MFMA GEMM + fused el/er epilogue, fp8 z ------
// z[Mpad][512] (fp8 e4m3) = A[Mpad][128] @ W1t[512][128]^T.  128x128 tile,
// 256 threads = 4 waves, each 64x64 via 4x4 mfma_16x16x32.  blockIdx.y = head
// (D=128 = tile width); el/er reduced from the fp32 accumulators (full
// precision — logits must not be quantized).  z fp8: payload only.
__global__ __launch_bounds__(256) void gemm1_kernel(
    const __hip_bfloat16* __restrict__ A,   // [Mpad][128] bf16
    const __hip_bfloat16* __restrict__ Bt,  // [512][128] bf16 (W1^T)
    unsigned char* __restrict__ C,          // [Mpad][512] fp8
    const float* __restrict__ al, const float* __restrict__ ar,
    float* __restrict__ el, float* __restrict__ er) {
  constexpr int K = 128;
  __shared__ short As[128 * 32];
  __shared__ short Bs[128 * 32];
  __shared__ float elbuf[4][128];
  __shared__ float erbuf[4][128];
  int t = threadIdx.x;
  int lane = t & 63;
  int wave = t >> 6;
  int rowBase = blockIdx.x * 128;
  int head = blockIdx.y;
  int colBase = head * 128;
  int woffr = (wave & 1) * 64;
  int woffc = (wave >> 1) * 64;
  int mrow = lane & 15, quad = lane >> 4;

  f32x4 acc[4][4];
#pragma unroll
  for (int i = 0; i < 4; ++i)
#pragma unroll
    for (int j = 0; j < 4; ++j) acc[i][j] = (f32x4){0.f, 0.f, 0.f, 0.f};

  for (int k0 = 0; k0 < K; k0 += 32) {
#pragma unroll
    for (int p = 0; p < 2; ++p) {
      int f = p * 256 + wave * 64 + lane;
      int r = f >> 2, kc = f & 3;
      gload16(A + (size_t)(rowBase + r) * K + k0 + kc * 8,
              As + p * 2048 + wave * 512);
      gload16(Bt + (size_t)(colBase + r) * K + k0 + kc * 8,
              Bs + p * 2048 + wave * 512);
    }
    __syncthreads();
    short8 af[4], bfr[4];
#pragma unroll
    for (int i = 0; i < 4; ++i)
      af[i] = *(const short8*)&As[(woffr + i * 16 + mrow) * 32 + quad * 8];
#pragma unroll
    for (int j = 0; j < 4; ++j)
      bfr[j] = *(const short8*)&Bs[(woffc + j * 16 + mrow) * 32 + quad * 8];
#pragma unroll
    for (int i = 0; i < 4; ++i)
#pragma unroll
      for (int j = 0; j < 4; ++j)
        acc[i][j] = __builtin_amdgcn_mfma_f32_16x16x32_bf16(af[i], bfr[j], acc[i][j], 0, 0, 0);
    __syncthreads();
  }

  // z store (fp8). C/D layout: col = lane&15, row = quad*4 + reg (m89/m91)
#pragma unroll
  for (int i = 0; i < 4; ++i) {
#pragma unroll
    for (int j = 0; j < 4; ++j) {
      int col = colBase + woffc + j * 16 + mrow;
#pragma unroll
      for (int r = 0; r < 4; ++r) {
        int row = rowBase + woffr + i * 16 + quad * 4 + r;
        C[(size_t)row * HD + col] = f32_to_fp8(acc[i][j][r]);
      }
    }
  }

  // fused el/er epilogue from fp32 accumulators
  float al_v[4], ar_v[4];
#pragma unroll
  for (int j = 0; j < 4; ++j) {
    int coll = woffc + j * 16 + mrow;
    al_v[j] = al[head * 128 + coll];
    ar_v[j] = ar[head * 128 + coll];
  }
#pragma unroll
  for (int i = 0; i < 4; ++i) {
#pragma unroll
    for (int r = 0; r < 4; ++r) {
      float pl = 0.f, pr = 0.f;
#pragma unroll
      for (int j = 0; j < 4; ++j) {
        float v = acc[i][j][r];
        pl += v * al_v[j];
        pr += v * ar_v[j];
      }
#pragma unroll
      for (int off = 1; off < 16; off <<= 1) {
        pl += __shfl_xor(pl, off);
        pr += __shfl_xor(pr, off);
      }
      if (mrow == 0) {
        int row128 = woffr + i * 16 + quad * 4 + r;
        elbuf[wave][row128] = pl;
        erbuf[wave][row128] = pr;
      }
    }
  }
  __syncthreads();
  if (t < 128) {
    int row = t;
    int w0 = (row < 64) ? 0 : 1;
    float ev = elbuf[w0][row] + elbuf[w0 + 2][row];
    float rv = erbuf[w0][row] + erbuf[w0 + 2][row];
    int gr = rowBase + row;
    if (gr < NN) {
      el[gr * 4 + head] = ev;
      er[gr * 4 + head] = rv;
    }
  }
}

// ---------------- fused attn + aggregation + layer-2 projection -------------
// One wave per node (proven R9 structure).
// Phase 1 (lane = slot): alpha via exp(leaky_relu(el1[src]+er1[n])) (softmax
// shift-invariance -> segment_max skipped), butterfly denom, alpha -> LDS.
// Phase 2 (lane = dims): h1[n, lane*8..+8) = ELU(sum_e alpha*z[src] + b1) in
// fp32 registers.
// Epilogue: h1 is NEVER stored — el2/er2/q are produced directly as 12 dot
// products with the W2-folded vcomb vectors (GEMM2 eliminated algebraically;
// logits stay fp32).
__global__ __launch_bounds__(256) void aggregate_kernel(
    const unsigned char* __restrict__ zf8,  // [MPAD][512] fp8
    const int* __restrict__ cnt,
    const int* __restrict__ src_perm,
    const float* __restrict__ el,           // layer-1 logits [NN][4]
    const float* __restrict__ er,
    const float* __restrict__ b1,           // [512]
    const float* __restrict__ vcomb,        // [12][512]
    float* __restrict__ el2,                // [NN][4]
    float* __restrict__ er2,                // [NN][4]
    float* __restrict__ q2) {               // [NN][4]
  __shared__ float4 alds[4][SLOTS];
  int wv = __builtin_amdgcn_readfirstlane((int)(threadIdx.x >> 6));
  int n = blockIdx.x * 4 + wv;
  int lane = threadIdx.x & 63;
  int c = min(cnt[n], SLOTS);
  int base = n * SLOTS;

  // ---- phase 1: attention coefficients (lane = slot) ----
  {
    float4 er4 = *reinterpret_cast<const float4*>(&er[n * 4]);
    float a0 = 0.f, a1 = 0.f, a2 = 0.f, a3 = 0.f;
    if (lane < c) {
      int s = src_perm[base + lane];
      float4 e4 = *reinterpret_cast<const float4*>(&el[s * 4]);
      float x0 = e4.x + er4.x, x1 = e4.y + er4.y;
      float x2 = e4.z + er4.z, x3 = e4.w + er4.w;
      x0 = (x0 > 0.f) ? x0 : NEG_SLOPE * x0;
      x1 = (x1 > 0.f) ? x1 : NEG_SLOPE * x1;
      x2 = (x2 > 0.f) ? x2 : NEG_SLOPE * x2;
      x3 = (x3 > 0.f) ? x3 : NEG_SLOPE * x3;
      a0 = __expf(x0); a1 = __expf(x1); a2 = __expf(x2); a3 = __expf(x3);
    }
    float s0 = a0, s1 = a1, s2 = a2, s3 = a3;
#pragma unroll
    for (int off = 1; off < 64; off <<= 1) {
      s0 += __shfl_xor(s0, off);
      s1 += __shfl_xor(s1, off);
      s2 += __shfl_xor(s2, off);
      s3 += __shfl_xor(s3, off);
    }
    float4 av;
    av.x = a0 / fmaxf(s0, 1e-9f);
    av.y = a1 / fmaxf(s1, 1e-9f);
    av.z = a2 / fmaxf(s2, 1e-9f);
    av.w = a3 / fmaxf(s3, 1e-9f);
    alds[wv][lane] = av;   // same-wave producer/consumer
  }

  // ---- phase 2: payload aggregation (lane = dims) ----
  int head = lane >> 4;
  float acc[8] = {};

#define EDGE_BODY(IDX)                                                         \
  {                                                                            \
    int s = src_perm[base + (IDX)];                                            \
    float4 a4 = alds[wv][(IDX)];                                               \
    float a = (head & 2) ? ((head & 1) ? a4.w : a4.z)                          \
                         : ((head & 1) ? a4.y : a4.x);                         \
    uint2 w = *reinterpret_cast<const uint2*>(zf8 + (size_t)s * 512 + lane * 8); \
    f32x2 f0 = __builtin_amdgcn_cvt_pk_f32_fp8(w.x, false);                    \
    f32x2 f1 = __builtin_amdgcn_cvt_pk_f32_fp8(w.x, true);                     \
    f32x2 f2 = __builtin_amdgcn_cvt_pk_f32_fp8(w.y, false);                    \
    f32x2 f3 = __builtin_amdgcn_cvt_pk_f32_fp8(w.y, true);                     \
    acc[0] += a * f0.x; acc[1] += a * f0.y;                                    \
    acc[2] += a * f1.x; acc[3] += a * f1.y;                                    \
    acc[4] += a * f2.x; acc[5] += a * f2.y;                                    \
    acc[6] += a * f3.x; acc[7] += a * f3.y;                                    \
  }

  int i = 0;
  for (; i + 3 < c; i += 4) {
    EDGE_BODY(i)
    EDGE_BODY(i + 1)
    EDGE_BODY(i + 2)
    EDGE_BODY(i + 3)
  }
  for (; i < c; ++i) EDGE_BODY(i)
#undef EDGE_BODY

  float4 bA = *reinterpret_cast<const float4*>(&b1[lane * 8]);
  float4 bB = *reinterpret_cast<const float4*>(&b1[lane * 8 + 4]);
  float v[8];
  v[0] = acc[0] + bA.x; v[1] = acc[1] + bA.y;
  v[2] = acc[2] + bA.z; v[3] = acc[3] + bA.w;
  v[4] = acc[4] + bB.x; v[5] = acc[5] + bB.y;
  v[6] = acc[6] + bB.z; v[7] = acc[7] + bB.w;
#pragma unroll
  for (int j = 0; j < 8; ++j) v[j] = (v[j] > 0.f) ? v[j] : expm1f(v[j]);

  // ---- epilogue: el2/er2/q = h1 . vcomb (12 dots, butterfly reductions) ----
  float r[12];
#pragma unroll
  for (int vv = 0; vv < 12; ++vv) {
    const float* vb = vcomb + vv * 512 + lane * 8;
    float4 cA = *reinterpret_cast<const float4*>(vb);
    float4 cB = *reinterpret_cast<const float4*>(vb + 4);
    float p = v[0] * cA.x + v[1] * cA.y + v[2] * cA.z + v[3] * cA.w +
              v[4] * cB.x + v[5] * cB.y + v[6] * cB.z + v[7] * cB.w;
#pragma unroll
    for (int off = 1; off < 64; off <<= 1) p += __shfl_xor(p, off);
    r[vv] = p;
  }
  if (lane == 0) {
    *reinterpret_cast<float4*>(&el2[n * 4]) = make_float4(r[0], r[1], r[2], r[3]);
    *reinterpret_cast<float4*>(&er2[n * 4]) = make_float4(r[4], r[5], r[6], r[7]);
    *reinterpret_cast<float4*>(&q2[n * 4]) = make_float4(r[8], r[9], r[10], r[11]);
  }
}

// ---------------- layer-2 attention + readout dot ---------------------------
// One wave per dst node (lane = slot): alpha butterfly, dot with q[src] (16 B
// L2-resident gather), block partial -> 256-slot atomics.  NO device fence /
// done counter — that cost ~90 µs in R11; a separate tiny final kernel is
// 30x cheaper.
__global__ __launch_bounds__(256) void attn_q_kernel(
    const int* __restrict__ src_perm,
    const int* __restrict__ cnt,
    const float* __restrict__ el,
    const float* __restrict__ er,
    const float* __restrict__ q,            // [NN][4]
    float* __restrict__ partials) {         // [256]
  __shared__ float blk[4];
  int wv = __builtin_amdgcn_readfirstlane((int)(threadIdx.x >> 6));
  int n = blockIdx.x * 4 + wv;
  int lane = threadIdx.x & 63;
  int c = min(cnt[n], SLOTS);
  float4 er4 = *reinterpret_cast<const float4*>(&er[n * 4]);
  float a0 = 0.f, a1 = 0.f, a2 = 0.f, a3 = 0.f;
  int s = 0;
  if (lane < c) {
    s = src_perm[n * SLOTS + lane];
    float4 e4 = *reinterpret_cast<const float4*>(&el[s * 4]);
    float x0 = e4.x + er4.x, x1 = e4.y + er4.y;
    float x2 = e4.z + er4.z, x3 = e4.w + er4.w;
    x0 = (x0 > 0.f) ? x0 : NEG_SLOPE * x0;
    x1 = (x1 > 0.f) ? x1 : NEG_SLOPE * x1;
    x2 = (x2 > 0.f) ? x2 : NEG_SLOPE * x2;
    x3 = (x3 > 0.f) ? x3 : NEG_SLOPE * x3;
    a0 = __expf(x0); a1 = __expf(x1); a2 = __expf(x2); a3 = __expf(x3);
  }
  float s0 = a0, s1 = a1, s2 = a2, s3 = a3;
#pragma unroll
  for (int off = 1; off < 64; off <<= 1) {
    s0 += __shfl_xor(s0, off);
    s1 += __shfl_xor(s1, off);
    s2 += __shfl_xor(s2, off);
    s3 += __shfl_xor(s3, off);
  }
  float p = 0.f;
  if (lane < c) {
    float4 q4 = *reinterpret_cast<const float4*>(&q[s * 4]);
    p = (a0 / fmaxf(s0, 1e-9f)) * q4.x + (a1 / fmaxf(s1, 1e-9f)) * q4.y +
        (a2 / fmaxf(s2, 1e-9f)) * q4.z + (a3 / fmaxf(s3, 1e-9f)) * q4.w;
  }
#pragma unroll
  for (int off = 32; off > 0; off >>= 1) p += __shfl_down(p, off);
  if (lane == 0) blk[wv] = p;
  __syncthreads();
  if (threadIdx.x == 0) {
    atomicAdd(&partials[blockIdx.x & 255], blk[0] + blk[1] + blk[2] + blk[3]);
  }
}

// ---------------- final: out = 0.25*(sum partials + NN*b2.Wr_rep) + NN*br ----
__global__ __launch_bounds__(512) void final_kernel(
    const float* __restrict__ partials, const float* __restrict__ b2,
    const float* __restrict__ Wr, const float* __restrict__ br,
    float* __restrict__ out) {
  __shared__ float tmp[512];
  int t = threadIdx.x;
  float sum = (t < 256) ? partials[t] : 0.f;
  sum += (float)NN * b2[t] * Wr[t & 127];
  tmp[t] = sum;
  __syncthreads();
  for (int off = 256; off > 0; off >>= 1) {
    if (t < off) tmp[t] += tmp[t + off];
    __syncthreads();
  }
  if (t == 0) out[0] = 0.25f * tmp[0] + (float)NN * br[0];
}

// ---------------- launch ----------------
extern "C" void kernel_launch(void* const* d_in, const int* in_sizes, int n_in,
                              void* d_out, int out_size, void* d_ws, size_t ws_size,
                              hipStream_t stream) {
  const float* feats = (const float*)d_in[0];
  const int* src = (const int*)d_in[1];
  const int* dst = (const int*)d_in[2];
  const float* W1 = (const float*)d_in[3];
  const float* al1 = (const float*)d_in[4];
  const float* ar1 = (const float*)d_in[5];
  const float* b1 = (const float*)d_in[6];
  const float* W2 = (const float*)d_in[7];
  const float* al2 = (const float*)d_in[8];
  const float* ar2 = (const float*)d_in[9];
  const float* b2 = (const float*)d_in[10];
  const float* Wr = (const float*)d_in[11];
  const float* br = (const float*)d_in[12];
  float* out = (float*)d_out;

  // workspace layout (~22 MB); all section sizes multiples of 16 B
  __hip_bfloat16* featsb = (__hip_bfloat16*)d_ws;               // MPAD*128 bf16
  unsigned char* zf8 = (unsigned char*)(featsb + (size_t)MPAD * 128); // MPAD*512 fp8
  __hip_bfloat16* W1t = (__hip_bfloat16*)(zf8 + (size_t)MPAD * HD);   // 512*128 bf16
  float* vcomb = (float*)(W1t + 512 * 128);                     // 12*512 f32
  float* el1 = vcomb + 12 * 512;                                // NN*4
  float* er1 = el1 + (size_t)NN * NHEAD;                        // NN*4
  float* el2 = er1 + (size_t)NN * NHEAD;                        // NN*4
  float* er2 = el2 + (size_t)NN * NHEAD;                        // NN*4
  float* q2 = er2 + (size_t)NN * NHEAD;                         // NN*4
  float* partials = q2 + (size_t)NN * NHEAD;                    // 256
  int* cnt = (int*)(partials + 256 + 4);                        // NN
  int* src_perm = cnt + NN;                                     // NN*SLOTS

  // cnt must be zero before prep's fill segment runs
  hipMemsetAsync(cnt, 0, NN * sizeof(int), stream);
  prep_kernel<<<(S4 + 255) / 256, 256, 0, stream>>>(
      feats, W1, W2, al2, ar2, Wr, src, dst, featsb, W1t, vcomb, partials,
      cnt, src_perm);

  dim3 gemm_grid(MPAD / 128, NHEAD);

  // ---- layer 1: GEMM (fp8 z + el/er) ----
  gemm1_kernel<<<gemm_grid, 256, 0, stream>>>(featsb, W1t, zf8, al1, ar1, el1, er1);

  // ---- fused: layer-1 attn+aggregate + layer-2 projections (GEMM2 folded) ---
  aggregate_kernel<<<NN / 4, 256, 0, stream>>>(zf8, cnt, src_perm, el1, er1, b1,
                                               vcomb, el2, er2, q2);

  // ---- layer-2 attention + readout dot, then tiny final reduce ----
  attn_q_kernel<<<NN / 4, 256, 0, stream>>>(src_perm, cnt, el2, er2, q2, partials);
  final_kernel<<<1, 512, 0, stream>>>(partials, b2, Wr, br, out);
}

// Round 13
// 176.364 us; speedup vs baseline: 1.4705x; 1.0141x over previous
//
#include <hip/hip_runtime.h>
#include <hip/hip_bf16.h>
#include <cstddef>

// Problem constants (match reference)
constexpr int NN = 20000;   // nodes
constexpr int NE = 320000;  // edges
constexpr int NHEAD = 4;
constexpr int ND = 128;     // per-head dim
constexpr int HD = 512;     // H*D
constexpr int MPAD = 20096; // 157*128 padded rows for GEMM tiles
constexpr int SLOTS = 64;   // padded-CSR slots per node (Poisson(16): P(>64)~1e-20)
constexpr float NEG_SLOPE = 0.2f;

using short8 = __attribute__((ext_vector_type(8))) short;
using f32x4 = __attribute__((ext_vector_type(4))) float;
using f32x2 = __attribute__((ext_vector_type(2))) float;

// async global->LDS, 16B per lane, LDS dest = wave-uniform base + lane*16
__device__ inline void gload16(const void* g, void* l) {
  __builtin_amdgcn_global_load_lds(
      (const __attribute__((address_space(1))) void*)g,
      (__attribute__((address_space(3))) void*)l, 16, 0, 0);
}

// fp8 e4m3 (OCP on gfx950) encode one float -> byte
__device__ inline unsigned char f32_to_fp8(float v) {
  int pk = __builtin_amdgcn_cvt_pk_fp8_f32(v, v, 0, false);
  return (unsigned char)(pk & 0xff);
}

// ---------------- fused prep --------------------------------------------------
// Segments: [cnt zero][feats->bf16 pad][W1^T bf16][vcomb][partials zero]
// (CSR fill moved to gemm1's prologue — saves the hipMemsetAsync dispatch;
//  prep zeroes cnt, gemm1 fills it, aggregate consumes it: stream-ordered.)
// vcomb[v][k], v = 0..11: v<4 -> vl[h=v], v<8 -> vr[h=v-4], else vq[h=v-8]:
//   vl[h,k] = sum_d W2[k, h*128+d] * al2[h,d]   (el2 = h1 . vl, fp32 — the
//   attention logits keep full precision; fp8 logits failed in R10)
constexpr int S0 = NN;                      // cnt zero
constexpr int S1 = S0 + MPAD * 128;         // featsb
constexpr int S2 = S1 + 512 * 128;          // W1t
constexpr int S3 = S2 + 12 * 512;           // vcomb
constexpr int S4 = S3 + 256;                // partials zero
__global__ __launch_bounds__(256) void prep_kernel(
    const float* __restrict__ feats, const float* __restrict__ W1,
    const float* __restrict__ W2, const float* __restrict__ al2,
    const float* __restrict__ ar2, const float* __restrict__ Wr,
    __hip_bfloat16* __restrict__ featsb, __hip_bfloat16* __restrict__ W1t,
    float* __restrict__ vcomb, float* __restrict__ partials,
    int* __restrict__ cnt) {
  int t = blockIdx.x * 256 + threadIdx.x;
  if (t < S0) {
    cnt[t] = 0;
  } else if (t < S1) {
    int u = t - S0;
    featsb[u] = __float2bfloat16(u < NN * 128 ? feats[u] : 0.f);
  } else if (t < S2) {
    int u = t - S1;                       // W1t[m][k], m=u>>7, k=u&127
    W1t[u] = __float2bfloat16(W1[(size_t)(u & 127) * 512 + (u >> 7)]);
  } else if (t < S3) {
    int u = t - S2;                       // vcomb[v][k]
    int v = u >> 9, k = u & 511;
    int h = (v < 4) ? v : (v < 8) ? v - 4 : v - 8;
    const float* vec = (v < 4) ? (al2 + h * 128)
                     : (v < 8) ? (ar2 + h * 128) : Wr;
    const float* wrow = W2 + (size_t)k * 512 + h * 128;
    float s = 0.f;
    for (int d = 0; d < 128; ++d) s += wrow[d] * vec[d];
    vcomb[u] = s;
  } else if (t < S4) {
    partials[t - S3] = 0.f;
  }
}

// ---------------- layer-1 bf16 MFMA GEMM + fused el/er epilogue, fp8 z ------
// Prologue: grid-stride padded-CSR fill (cnt zeroed by prep).
// z[Mpad][512] (fp8 e4m3) = A[Mpad][128] @ W1t[512][128]^T.  128x128 tile,
// 256 threads = 4 waves, each 64x64 via 4x4 mfma_16x16x32.  blockIdx.y = head
// (D=128 = tile width); el/er reduced from the fp32 accumulators (full
// precision — logits must not be quantized).  z fp8: payload only.
__global__ __launch_bounds__(256) void gemm1_kernel(
    const __hip_bfloat16* __restrict__ A,   // [Mpad][128] bf16
    const __hip_bfloat16* __restrict__ Bt,  // [512][128] bf16 (W1^T)
    unsigned char* __restrict__ C,          // [Mpad][512] fp8
    const float* __restrict__ al, const float* __restrict__ ar,
    float* __restrict__ el, float* __restrict__ er,
    const int* __restrict__ src, const int* __restrict__ dst,
    int* __restrict__ cnt, int* __restrict__ src_perm) {
  constexpr int K = 128;
  __shared__ short As[128 * 32];
  __shared__ short Bs[128 * 32];
  __shared__ float elbuf[4][128];
  __shared__ float erbuf[4][128];
  int t = threadIdx.x;

  // ---- CSR fill prologue (completes before aggregate by stream order) ----
  {
    int nth = gridDim.x * gridDim.y * 256;
    int gid = (blockIdx.y * gridDim.x + blockIdx.x) * 256 + t;
    for (int e = gid; e < NE; e += nth) {
      int d = dst[e];
      int p = atomicAdd(&cnt[d], 1);
      if (p < SLOTS) src_perm[d * SLOTS + p] = src[e];
    }
  }

  int lane = t & 63;
  int wave = t >> 6;
  int rowBase = blockIdx.x * 128;
  int head = blockIdx.y;
  int colBase = head * 128;
  int woffr = (wave & 1) * 64;
  int woffc = (wave >> 1) * 64;
  int mrow = lane & 15, quad = lane >> 4;

  f32x4 acc[4][4];
#pragma unroll
  for (int i = 0; i < 4; ++i)
#pragma unroll
    for (int j = 0; j < 4; ++j) acc[i][j] = (f32x4){0.f, 0.f, 0.f, 0.f};

  for (int k0 = 0; k0 < K; k0 += 32) {
#pragma unroll
    for (int p = 0; p < 2; ++p) {
      int f = p * 256 + wave * 64 + lane;
      int r = f >> 2, kc = f & 3;
      gload16(A + (size_t)(rowBase + r) * K + k0 + kc * 8,
              As + p * 2048 + wave * 512);
      gload16(Bt + (size_t)(colBase + r) * K + k0 + kc * 8,
              Bs + p * 2048 + wave * 512);
    }
    __syncthreads();
    short8 af[4], bfr[4];
#pragma unroll
    for (int i = 0; i < 4; ++i)
      af[i] = *(const short8*)&As[(woffr + i * 16 + mrow) * 32 + quad * 8];
#pragma unroll
    for (int j = 0; j < 4; ++j)
      bfr[j] = *(const short8*)&Bs[(woffc + j * 16 + mrow) * 32 + quad * 8];
#pragma unroll
    for (int i = 0; i < 4; ++i)
#pragma unroll
      for (int j = 0; j < 4; ++j)
        acc[i][j] = __builtin_amdgcn_mfma_f32_16x16x32_bf16(af[i], bfr[j], acc[i][j], 0, 0, 0);
    __syncthreads();
  }

  // z store (fp8). C/D layout: col = lane&15, row = quad*4 + reg (m89/m91)
#pragma unroll
  for (int i = 0; i < 4; ++i) {
#pragma unroll
    for (int j = 0; j < 4; ++j) {
      int col = colBase + woffc + j * 16 + mrow;
#pragma unroll
      for (int r = 0; r < 4; ++r) {
        int row = rowBase + woffr + i * 16 + quad * 4 + r;
        C[(size_t)row * HD + col] = f32_to_fp8(acc[i][j][r]);
      }
    }
  }

  // fused el/er epilogue from fp32 accumulators
  float al_v[4], ar_v[4];
#pragma unroll
  for (int j = 0; j < 4; ++j) {
    int coll = woffc + j * 16 + mrow;
    al_v[j] = al[head * 128 + coll];
    ar_v[j] = ar[head * 128 + coll];
  }
#pragma unroll
  for (int i = 0; i < 4; ++i) {
#pragma unroll
    for (int r = 0; r < 4; ++r) {
      float pl = 0.f, pr = 0.f;
#pragma unroll
      for (int j = 0; j < 4; ++j) {
        float v = acc[i][j][r];
        pl += v * al_v[j];
        pr += v * ar_v[j];
      }
#pragma unroll
      for (int off = 1; off < 16; off <<= 1) {
        pl += __shfl_xor(pl, off);
        pr += __shfl_xor(pr, off);
      }
      if (mrow == 0) {
        int row128 = woffr + i * 16 + quad * 4 + r;
        elbuf[wave][row128] = pl;
        erbuf[wave][row128] = pr;
      }
    }
  }
  __syncthreads();
  if (t < 128) {
    int row = t;
    int w0 = (row < 64) ? 0 : 1;
    float ev = elbuf[w0][row] + elbuf[w0 + 2][row];
    float rv = erbuf[w0][row] + erbuf[w0 + 2][row];
    int gr = rowBase + row;
    if (gr < NN) {
      el[gr * 4 + head] = ev;
      er[gr * 4 + head] = rv;
    }
  }
}

// ---------------- fused attn + aggregation + layer-2 projection -------------
// One wave per node.
// Phase 1 (lane = slot): alpha via exp(leaky_relu(el1[src]+er1[n])) (softmax
// shift-invariance -> segment_max skipped), butterfly denom; alpha parked in
// LDS TRANSPOSED [wave][head][slot] so phase 2 reads one ds_read_b32/edge.
// Phase 2 (lane = dims, 8-deep unroll -> 8 outstanding gathers): h1 in fp32
// registers = ELU(sum_e alpha*z[src] + b1).
// Epilogue: h1 never stored — el2/er2/q are 12 dot products with the
// W2-folded vcomb vectors (GEMM2 eliminated algebraically; logits fp32).
__global__ __launch_bounds__(256) void aggregate_kernel(
    const unsigned char* __restrict__ zf8,  // [MPAD][512] fp8
    const int* __restrict__ cnt,
    const int* __restrict__ src_perm,
    const float* __restrict__ el,           // layer-1 logits [NN][4]
    const float* __restrict__ er,
    const float* __restrict__ b1,           // [512]
    const float* __restrict__ vcomb,        // [12][512]
    float* __restrict__ el2,                // [NN][4]
    float* __restrict__ er2,                // [NN][4]
    float* __restrict__ q2) {               // [NN][4]
  __shared__ float aldsT[4][4][66];         // [wave][head][slot]; 66: bank-spread
  int wv = __builtin_amdgcn_readfirstlane((int)(threadIdx.x >> 6));
  int n = blockIdx.x * 4 + wv;
  int lane = threadIdx.x & 63;
  int c = min(cnt[n], SLOTS);
  int base = n * SLOTS;

  // ---- phase 1: attention coefficients (lane = slot) ----
  {
    float4 er4 = *reinterpret_cast<const float4*>(&er[n * 4]);
    float a0 = 0.f, a1 = 0.f, a2 = 0.f, a3 = 0.f;
    if (lane < c) {
      int s = src_perm[base + lane];
      float4 e4 = *reinterpret_cast<const float4*>(&el[s * 4]);
      float x0 = e4.x + er4.x, x1 = e4.y + er4.y;
      float x2 = e4.z + er4.z, x3 = e4.w + er4.w;
      x0 = (x0 > 0.f) ? x0 : NEG_SLOPE * x0;
      x1 = (x1 > 0.f) ? x1 : NEG_SLOPE * x1;
      x2 = (x2 > 0.f) ? x2 : NEG_SLOPE * x2;
      x3 = (x3 > 0.f) ? x3 : NEG_SLOPE * x3;
      a0 = __expf(x0); a1 = __expf(x1); a2 = __expf(x2); a3 = __expf(x3);
    }
    float s0 = a0, s1 = a1, s2 = a2, s3 = a3;
#pragma unroll
    for (int off = 1; off < 64; off <<= 1) {
      s0 += __shfl_xor(s0, off);
      s1 += __shfl_xor(s1, off);
      s2 += __shfl_xor(s2, off);
      s3 += __shfl_xor(s3, off);
    }
    aldsT[wv][0][lane] = a0 / fmaxf(s0, 1e-9f);
    aldsT[wv][1][lane] = a1 / fmaxf(s1, 1e-9f);
    aldsT[wv][2][lane] = a2 / fmaxf(s2, 1e-9f);
    aldsT[wv][3][lane] = a3 / fmaxf(s3, 1e-9f);   // same-wave producer/consumer
  }

  // ---- phase 2: payload aggregation (lane = dims), 8 gathers in flight ----
  int head = lane >> 4;
  const float* arow = &aldsT[wv][head][0];
  float acc[8] = {};

#define EDGE_BODY(IDX)                                                         \
  {                                                                            \
    int s = src_perm[base + (IDX)];                                            \
    float a = arow[(IDX)];                                                     \
    uint2 w = *reinterpret_cast<const uint2*>(zf8 + (size_t)s * 512 + lane * 8); \
    f32x2 f0 = __builtin_amdgcn_cvt_pk_f32_fp8(w.x, false);                    \
    f32x2 f1 = __builtin_amdgcn_cvt_pk_f32_fp8(w.x, true);                     \
    f32x2 f2 = __builtin_amdgcn_cvt_pk_f32_fp8(w.y, false);                    \
    f32x2 f3 = __builtin_amdgcn_cvt_pk_f32_fp8(w.y, true);                     \
    acc[0] += a * f0.x; acc[1] += a * f0.y;                                    \
    acc[2] += a * f1.x; acc[3] += a * f1.y;                                    \
    acc[4] += a * f2.x; acc[5] += a * f2.y;                                    \
    acc[6] += a * f3.x; acc[7] += a * f3.y;                                    \
  }

  int i = 0;
  for (; i + 7 < c; i += 8) {
    EDGE_BODY(i)
    EDGE_BODY(i + 1)
    EDGE_BODY(i + 2)
    EDGE_BODY(i + 3)
    EDGE_BODY(i + 4)
    EDGE_BODY(i + 5)
    EDGE_BODY(i + 6)
    EDGE_BODY(i + 7)
  }
  for (; i < c; ++i) EDGE_BODY(i)
#undef EDGE_BODY

  float4 bA = *reinterpret_cast<const float4*>(&b1[lane * 8]);
  float4 bB = *reinterpret_cast<const float4*>(&b1[lane * 8 + 4]);
  float v[8];
  v[0] = acc[0] + bA.x; v[1] = acc[1] + bA.y;
  v[2] = acc[2] + bA.z; v[3] = acc[3] + bA.w;
  v[4] = acc[4] + bB.x; v[5] = acc[5] + bB.y;
  v[6] = acc[6] + bB.z; v[7] = acc[7] + bB.w;
#pragma unroll
  for (int j = 0; j < 8; ++j) v[j] = (v[j] > 0.f) ? v[j] : expm1f(v[j]);

  // ---- epilogue: el2/er2/q = h1 . vcomb (12 dots, butterfly reductions) ----
  float r[12];
#pragma unroll
  for (int vv = 0; vv < 12; ++vv) {
    const float* vb = vcomb + vv * 512 + lane * 8;
    float4 cA = *reinterpret_cast<const float4*>(vb);
    float4 cB = *reinterpret_cast<const float4*>(vb + 4);
    float p = v[0] * cA.x + v[1] * cA.y + v[2] * cA.z + v[3] * cA.w +
              v[4] * cB.x + v[5] * cB.y + v[6] * cB.z + v[7] * cB.w;
#pragma unroll
    for (int off = 1; off < 64; off <<= 1) p += __shfl_xor(p, off);
    r[vv] = p;
  }
  if (lane == 0) {
    *reinterpret_cast<float4*>(&el2[n * 4]) = make_float4(r[0], r[1], r[2], r[3]);
    *reinterpret_cast<float4*>(&er2[n * 4]) = make_float4(r[4], r[5], r[6], r[7]);
    *reinterpret_cast<float4*>(&q2[n * 4]) = make_float4(r[8], r[9], r[10], r[11]);
  }
}

// ---------------- layer-2 attention + readout dot ---------------------------
// One wave per dst node (lane = slot): alpha butterfly, dot with q[src] (16 B
// L2-resident gather), block partial -> 256-slot atomics.  NO device fence /
// done counter — that cost ~90 µs in R11; the tiny final kernel is cheaper.
__global__ __launch_bounds__(256) void attn_q_kernel(
    const int* __restrict__ src_perm,
    const int* __restrict__ cnt,
    const float* __restrict__ el,
    const float* __restrict__ er,
    const float* __restrict__ q,            // [NN][4]
    float* __restrict__ partials) {         // [256]
  __shared__ float blk[4];
  int wv = __builtin_amdgcn_readfirstlane((int)(threadIdx.x >> 6));
  int n = blockIdx.x * 4 + wv;
  int lane = threadIdx.x & 63;
  int c = min(cnt[n], SLOTS);
  float4 er4 = *reinterpret_cast<const float4*>(&er[n * 4]);
  float a0 = 0.f, a1 = 0.f, a2 = 0.f, a3 = 0.f;
  int s = 0;
  if (lane < c) {
    s = src_perm[n * SLOTS + lane];
    float4 e4 = *reinterpret_cast<const float4*>(&el[s * 4]);
    float x0 = e4.x + er4.x, x1 = e4.y + er4.y;
    float x2 = e4.z + er4.z, x3 = e4.w + er4.w;
    x0 = (x0 > 0.f) ? x0 : NEG_SLOPE * x0;
    x1 = (x1 > 0.f) ? x1 : NEG_SLOPE * x1;
    x2 = (x2 > 0.f) ? x2 : NEG_SLOPE * x2;
    x3 = (x3 > 0.f) ? x3 : NEG_SLOPE * x3;
    a0 = __expf(x0); a1 = __expf(x1); a2 = __expf(x2); a3 = __expf(x3);
  }
  float s0 = a0, s1 = a1, s2 = a2, s3 = a3;
#pragma unroll
  for (int off = 1; off < 64; off <<= 1) {
    s0 += __shfl_xor(s0, off);
    s1 += __shfl_xor(s1, off);
    s2 += __shfl_xor(s2, off);
    s3 += __shfl_xor(s3, off);
  }
  float p = 0.f;
  if (lane < c) {
    float4 q4 = *reinterpret_cast<const float4*>(&q[s * 4]);
    p = (a0 / fmaxf(s0, 1e-9f)) * q4.x + (a1 / fmaxf(s1, 1e-9f)) * q4.y +
        (a2 / fmaxf(s2, 1e-9f)) * q4.z + (a3 / fmaxf(s3, 1e-9f)) * q4.w;
  }
#pragma unroll
  for (int off = 32; off > 0; off >>= 1) p += __shfl_down(p, off);
  if (lane == 0) blk[wv] = p;
  __syncthreads();
  if (threadIdx.x == 0) {
    atomicAdd(&partials[blockIdx.x & 255], blk[0] + blk[1] + blk[2] + blk[3]);
  }
}

// ---------------- final: out = 0.25*(sum partials + NN*b2.Wr_rep) + NN*br ----
__global__ __launch_bounds__(512) void final_kernel(
    const float* __restrict__ partials, const float* __restrict__ b2,
    const float* __restrict__ Wr, const float* __restrict__ br,
    float* __restrict__ out) {
  __shared__ float tmp[512];
  int t = threadIdx.x;
  float sum = (t < 256) ? partials[t] : 0.f;
  sum += (float)NN * b2[t] * Wr[t & 127];
  tmp[t] = sum;
  __syncthreads();
  for (int off = 256; off > 0; off >>= 1) {
    if (t < off) tmp[t] += tmp[t + off];
    __syncthreads();
  }
  if (t == 0) out[0] = 0.25f * tmp[0] + (float)NN * br[0];
}

// ---------------- launch ----------------
extern "C" void kernel_launch(void* const* d_in, const int* in_sizes, int n_in,
                              void* d_out, int out_size, void* d_ws, size_t ws_size,
                              hipStream_t stream) {
  const float* feats = (const float*)d_in[0];
  const int* src = (const int*)d_in[1];
  const int* dst = (const int*)d_in[2];
  const float* W1 = (const float*)d_in[3];
  const float* al1 = (const float*)d_in[4];
  const float* ar1 = (const float*)d_in[5];
  const float* b1 = (const float*)d_in[6];
  const float* W2 = (const float*)d_in[7];
  const float* al2 = (const float*)d_in[8];
  const float* ar2 = (const float*)d_in[9];
  const float* b2 = (const float*)d_in[10];
  const float* Wr = (const float*)d_in[11];
  const float* br = (const float*)d_in[12];
  float* out = (float*)d_out;

  // workspace layout (~22 MB); all section sizes multiples of 16 B
  __hip_bfloat16* featsb = (__hip_bfloat16*)d_ws;               // MPAD*128 bf16
  unsigned char* zf8 = (unsigned char*)(featsb + (size_t)MPAD * 128); // MPAD*512 fp8
  __hip_bfloat16* W1t = (__hip_bfloat16*)(zf8 + (size_t)MPAD * HD);   // 512*128 bf16
  float* vcomb = (float*)(W1t + 512 * 128);                     // 12*512 f32
  float* el1 = vcomb + 12 * 512;                                // NN*4
  float* er1 = el1 + (size_t)NN * NHEAD;                        // NN*4
  float* el2 = er1 + (size_t)NN * NHEAD;                        // NN*4
  float* er2 = el2 + (size_t)NN * NHEAD;                        // NN*4
  float* q2 = er2 + (size_t)NN * NHEAD;                         // NN*4
  float* partials = q2 + (size_t)NN * NHEAD;                    // 256
  int* cnt = (int*)(partials + 256 + 4);                        // NN
  int* src_perm = cnt + NN;                                     // NN*SLOTS

  // prep: cnt zero + feats->bf16 + W1^T + vcomb + partials zero (1 dispatch)
  prep_kernel<<<(S4 + 255) / 256, 256, 0, stream>>>(
      feats, W1, W2, al2, ar2, Wr, featsb, W1t, vcomb, partials, cnt);

  dim3 gemm_grid(MPAD / 128, NHEAD);

  // gemm1: CSR-fill prologue + GEMM (fp8 z + el/er epilogue)
  gemm1_kernel<<<gemm_grid, 256, 0, stream>>>(featsb, W1t, zf8, al1, ar1,
                                              el1, er1, src, dst, cnt, src_perm);

  // fused: layer-1 attn+aggregate + layer-2 projections (GEMM2 folded)
  aggregate_kernel<<<NN / 4, 256, 0, stream>>>(zf8, cnt, src_perm, el1, er1, b1,
                                               vcomb, el2, er2, q2);

  // layer-2 attention + readout dot, then tiny final reduce
  attn_q_kernel<<<NN / 4, 256, 0, stream>>>(src_perm, cnt, el2, er2, q2, partials);
  final_kernel<<<1, 512, 0, stream>>>(partials, b2, Wr, br, out);
}